// Round 12
// baseline (792.802 us; speedup 1.0000x reference)
//
#include <hip/hip_runtime.h>

// ---------------------------------------------------------------------------
// Llama4TextExperts: per-expert  out = (up * silu(gate)) @ W2
// E=8, T=8192 (1024/expert), H=2048, I=4096, fp32 in/out, bf16 MFMA compute.
// R12: single-round gemm1 — grid 256, each block loops 4 nb panels with the
//      pipeline flowing across boundaries (no drain). Tests the measured
//      per-round overhead (4 rounds @ x~58us). SiLU re-fused (R5 epilogue).
//      Inner phase bodies byte-identical to R5/R11 (passed 3x).
// ---------------------------------------------------------------------------

#define E_   8
#define H_   2048
#define I_   4096
#define T_   8192
#define TPE  1024

typedef __bf16 bf16x8 __attribute__((ext_vector_type(8)));
typedef float  f32x4  __attribute__((ext_vector_type(4)));

__device__ __forceinline__ unsigned short f2bf(float f) {
  union { float f; unsigned int u; } v; v.f = f;
  unsigned int u = v.u;
  u += 0x7FFFu + ((u >> 16) & 1u);   // RNE
  return (unsigned short)(u >> 16);
}

__device__ __forceinline__ void async16(const void* g, void* l) {
  __builtin_amdgcn_global_load_lds(
      (__attribute__((address_space(1))) void*)(g),
      (__attribute__((address_space(3))) void*)(l), 16, 0, 0);
}

#define SB0()      __builtin_amdgcn_sched_barrier(0)
#define BAR()      __builtin_amdgcn_s_barrier()
#define WAITLGKM() asm volatile("s_waitcnt lgkmcnt(0)" ::: "memory")
#define WAITVM(n)  asm volatile("s_waitcnt vmcnt(" #n ")" ::: "memory")

// ---------------------------------------------------------------------------
__global__ void convert_bf16(const float* __restrict__ src,
                             unsigned short* __restrict__ dst, long n) {
  long i = ((long)blockIdx.x * blockDim.x + threadIdx.x) * 4;
  const long stride = (long)gridDim.x * blockDim.x * 4;
  for (; i < n; i += stride) {
    const float4 v = *(const float4*)&src[i];
    ushort4 o;
    o.x = f2bf(v.x); o.y = f2bf(v.y); o.z = f2bf(v.z); o.w = f2bf(v.w);
    *(ushort4*)&dst[i] = o;
  }
}

// ---------------------------------------------------------------------------
// 256x256x64 8-phase GEMM, NBL nb-panels per block (pipeline flows across
// panel boundaries; per-panel epilogue has no barriers / no LDS).
// A: bf16 (M,K) via global_load_lds (pre-swizzled source).  B: fp32 (K,N),
// per-thread float4 along N (lane owns 4 contiguous cols = storage rows
// 4*lane..+3; wave = k-octet), reg transpose -> bf16x8 -> ds_write_b128 at
// slot = wave^(lane&7).  Frag reads: A key lr&7; B quad-XOR (R5 pattern,
// 2.5e7 conflicts measured benign in R9 A/B).
// vmcnt ledger per tile (issue [P1: A q0(t+2) x2][P2: B(t+2) x8]
// [P3: A q1(t+2) x2]): P2 WAITVM(4) retires B(t+1); P3 WAITVM(12) retires
// A q1(t+1).  Boundary-epilogue global stores enter the queue AFTER all
// items the waits protect -> every wait stays conservative-correct.
// ---------------------------------------------------------------------------
template <int K, int NBL, int NBN, int LDB, bool SILU>
__global__ __launch_bounds__(512, 2)
void gemm_fused(const unsigned short* __restrict__ Aall,
                const float* __restrict__ Ball,
                void* __restrict__ Cout,
                long sA, long sB, long sC) {
  extern __shared__ char smem[];
  constexpr int NT  = K / 64;
  constexpr int TTN = NT * NBL;

  const int tid  = threadIdx.x;
  const int wave = tid >> 6;
  const int lane = tid & 63;
  const int lr   = lane & 15;
  const int lq   = lane >> 4;
  const int wid_m = wave >> 2;     // 0..1
  const int wid_n = wave & 3;      // 0..3

  // T1: bijective XCD swizzle (gridDim.x % 8 == 0), mb innermost so the 4
  // mb partners sharing each B panel are consecutive -> same XCD L2.
  const int nwg = gridDim.x;
  const int bid = blockIdx.x;
  const int wg  = (bid & 7) * (nwg >> 3) + (bid >> 3);
  constexpr int NBG = NBN / NBL;
  const int mb  = wg & 3;
  const int nbg = (wg >> 2) % NBG;
  const int e   = wg / (4 * NBG);
  const int nb0 = nbg * NBL;

  const unsigned short* A = Aall + (long)e * sA + (long)(mb * 256) * K;
  const float*          B = Ball + (long)e * sB;

  // ---- A staging (global_load_lds, pre-swizzled source); kt only --------
  const int stl  = tid >> 3;                      // 0..63
  const int scol = ((tid & 7) ^ (stl & 7)) * 8;   // swizzled src elem col

  auto stageA = [&](int bi, int q, int ttArg) {
    const int  kt  = ttArg % NT;
    const long col = (long)kt * 64 + scol;
    char* l0 = smem + bi * 32768 + q * 16384 + wave * 1024;
    async16(A + (long)(q * 64 + stl) * K + col,        l0);
    async16(A + (long)(128 + q * 64 + stl) * K + col,  l0 + 8192);
  };

  // ---- B: lane owns storage rows 4*lane..+3 = 4 contiguous global cols ---
  int colq0;   // global col of storage row st=4*lane, at nb = nb0
  {
    const int st = 4 * lane;
    const int b  = st >> 7;
    const int r  = st & 127;
    const int w  = r >> 5;
    const int nf = (r >> 4) & 1;
    const int l4 = st & 15;
    if (SILU) colq0 = nb0 * 128 + (w * 32 + b * 16 + l4) + (nf ? I_ : 0);
    else      colq0 = nb0 * 256 + w * 64 + (b * 2 + nf) * 16 + l4;
  }
  const float* Bq = B + colq0;
  constexpr int NBSTEP = SILU ? 128 : 256;   // column shift per nbi

  f32x4 bv[8];
  auto LOADB = [&](int ttArg) {
    const int  nbi   = ttArg / NT;
    const int  kt    = ttArg % NT;
    const long kbase = (long)kt * 64 + wave * 8;
    const float* p   = Bq + nbi * NBSTEP;
#pragma unroll
    for (int i = 0; i < 8; ++i)
      bv[i] = *(const f32x4*)&p[(kbase + i) * (long)LDB];
  };
  auto WRITEB = [&](int bo) {
    char* LBw = smem + 65536 + bo * 32768;
    const int slot = wave ^ (lane & 7);
#pragma unroll
    for (int j = 0; j < 4; ++j) {
      bf16x8 pk;
#pragma unroll
      for (int i = 0; i < 8; ++i) pk[i] = (__bf16)bv[i][j];
      const int st = 4 * lane + j;
      *(bf16x8*)(LBw + st * 128 + slot * 16) = pk;
    }
  };

  // fragment-read swizzled slot offsets (R5 pattern)
  const int axA0 = ((0 + lq) ^ (lr & 7)) * 16;      // A: k 0..31
  const int axA1 = ((4 + lq) ^ (lr & 7)) * 16;      // A: k 32..63
  const int bxn[2] = { (lr >> 2), 4 + (lr >> 2) };  // B row-quad XOR per nf

  f32x4 acc[8][4];
#pragma unroll
  for (int m = 0; m < 8; ++m)
#pragma unroll
    for (int n = 0; n < 4; ++n) acc[m][n] = (f32x4)0.0f;

  // ---- per-panel epilogue (no LDS, no barriers) + acc reset --------------
  auto epilogue = [&](int nbi) {
    const int nb = nb0 + nbi;
    if (SILU) {
      unsigned short* Cc = (unsigned short*)Cout + (long)e * sC;
#pragma unroll
      for (int mf = 0; mf < 8; ++mf)
#pragma unroll
        for (int p = 0; p < 2; ++p)
#pragma unroll
          for (int rr = 0; rr < 4; ++rr) {
            const int row = mb * 256 + wid_m * 128 + mf * 16 + lq * 4 + rr;
            const int col = nb * 128 + wid_n * 32 + p * 16 + lr;
            const float g = acc[mf][p * 2][rr];
            const float u = acc[mf][p * 2 + 1][rr];
            Cc[(long)row * I_ + col] = f2bf(u * (g / (1.0f + __expf(-g))));
          }
    } else {
      float* Cc = (float*)Cout + (long)e * sC;
#pragma unroll
      for (int mf = 0; mf < 8; ++mf)
#pragma unroll
        for (int q = 0; q < 4; ++q)
#pragma unroll
          for (int rr = 0; rr < 4; ++rr) {
            const int row = mb * 256 + wid_m * 128 + mf * 16 + lq * 4 + rr;
            const int col = nb * 256 + wid_n * 64 + q * 16 + lr;
            Cc[(long)row * H_ + col] = acc[mf][q][rr];
          }
    }
#pragma unroll
    for (int m = 0; m < 8; ++m)
#pragma unroll
      for (int n = 0; n < 4; ++n) acc[m][n] = (f32x4)0.0f;
  };

  // ---------------- prologue (tiles 0,1) --------------------------------
  LOADB(0);                    // 8 f4  B(0)
  stageA(0, 0, 0);             // 2 a16
  stageA(0, 1, 0);             // 2 a16
  SB0();
  WAITVM(4); SB0();            // B(0) done (leaves A(0) 4)
  WRITEB(0);
  WAITLGKM(); SB0();           // publish B(0); free bv (WAR)
  stageA(1, 0, 1); SB0();      // 2  A(1)q0
  LOADB(1); SB0();             // 8  B(1)
  stageA(1, 1, 1); SB0();      // 2  A(1)q1
  WAITVM(12); SB0();           // drain A(0); leaves [2,8,2]
  BAR();

  // ---------------- tile body (R5 phases, tt-indexed) --------------------
  auto body = [&](int tt) {
    const int cur = tt & 1;
    const int bo  = cur ^ 1;
    const char* LA = smem + cur * 32768;
    const char* LB = smem + 65536 + cur * 32768;
    const int t2v = (tt + 2 < TTN) ? tt + 2 : TTN - 1;

    bf16x8 a[4][2], b0[2][2], b1[2][2];

    // ---- P0: read a(q0)+b0; no VMEM ------------------------------------
#pragma unroll
    for (int mf = 0; mf < 4; ++mf) {
      const int st = wid_m * 64 + mf * 16 + lr;
      a[mf][0] = *(const bf16x8*)(LA + st * 128 + axA0);
      a[mf][1] = *(const bf16x8*)(LA + st * 128 + axA1);
    }
#pragma unroll
    for (int nf = 0; nf < 2; ++nf) {
      const int st = wid_n * 32 + nf * 16 + lr;
      b0[nf][0] = *(const bf16x8*)(LB + st * 128 + ((0 + lq) ^ bxn[nf]) * 16);
      b0[nf][1] = *(const bf16x8*)(LB + st * 128 + ((4 + lq) ^ bxn[nf]) * 16);
    }
    SB0();
    BAR();
    WAITLGKM(); SB0();
    __builtin_amdgcn_s_setprio(1);
#pragma unroll
    for (int mf = 0; mf < 4; ++mf)
#pragma unroll
      for (int nf = 0; nf < 2; ++nf) {
        acc[mf][nf] = __builtin_amdgcn_mfma_f32_16x16x32_bf16(a[mf][0], b0[nf][0], acc[mf][nf], 0, 0, 0);
        acc[mf][nf] = __builtin_amdgcn_mfma_f32_16x16x32_bf16(a[mf][1], b0[nf][1], acc[mf][nf], 0, 0, 0);
      }
    __builtin_amdgcn_s_setprio(0);
    BAR();

    // ---- P1: read b1; issue A(t+2)q0 -----------------------------------
#pragma unroll
    for (int nf = 0; nf < 2; ++nf) {
      const int st = 128 + wid_n * 32 + nf * 16 + lr;
      b1[nf][0] = *(const bf16x8*)(LB + st * 128 + ((0 + lq) ^ bxn[nf]) * 16);
      b1[nf][1] = *(const bf16x8*)(LB + st * 128 + ((4 + lq) ^ bxn[nf]) * 16);
    }
    stageA(cur, 0, t2v);
    SB0();
    BAR();
    WAITLGKM(); SB0();
    __builtin_amdgcn_s_setprio(1);
#pragma unroll
    for (int mf = 0; mf < 4; ++mf)
#pragma unroll
      for (int nf = 0; nf < 2; ++nf) {
        acc[mf][2 + nf] = __builtin_amdgcn_mfma_f32_16x16x32_bf16(a[mf][0], b1[nf][0], acc[mf][2 + nf], 0, 0, 0);
        acc[mf][2 + nf] = __builtin_amdgcn_mfma_f32_16x16x32_bf16(a[mf][1], b1[nf][1], acc[mf][2 + nf], 0, 0, 0);
      }
    __builtin_amdgcn_s_setprio(0);
    BAR();

    // ---- P2: read a(q1); vmcnt(4) -> write B(t+1); issue B(t+2) --------
#pragma unroll
    for (int mf = 0; mf < 4; ++mf) {
      const int st = 128 + wid_m * 64 + mf * 16 + lr;
      a[mf][0] = *(const bf16x8*)(LA + st * 128 + axA0);
      a[mf][1] = *(const bf16x8*)(LA + st * 128 + axA1);
    }
    SB0();
    WAITVM(4); SB0();          // B(t+1) regs ready
    WRITEB(bo);
    WAITLGKM(); SB0();         // drain a(q1) reads + B writes (WAR on bv)
    LOADB(t2v);                // 8 f4  B(t+2)
    SB0();
    BAR();
    __builtin_amdgcn_s_setprio(1);
#pragma unroll
    for (int mf = 0; mf < 4; ++mf)
#pragma unroll
      for (int nf = 0; nf < 2; ++nf) {
        acc[4 + mf][2 + nf] = __builtin_amdgcn_mfma_f32_16x16x32_bf16(a[mf][0], b1[nf][0], acc[4 + mf][2 + nf], 0, 0, 0);
        acc[4 + mf][2 + nf] = __builtin_amdgcn_mfma_f32_16x16x32_bf16(a[mf][1], b1[nf][1], acc[4 + mf][2 + nf], 0, 0, 0);
      }
    __builtin_amdgcn_s_setprio(0);
    BAR();

    // ---- P3: issue A(t+2)q1; vmcnt(12); MFMA on regs -------------------
    stageA(cur, 1, t2v);
    SB0();
    WAITVM(12); SB0();         // retires A q1(t+1)
    BAR();
    __builtin_amdgcn_s_setprio(1);
#pragma unroll
    for (int mf = 0; mf < 4; ++mf)
#pragma unroll
      for (int nf = 0; nf < 2; ++nf) {
        acc[4 + mf][nf] = __builtin_amdgcn_mfma_f32_16x16x32_bf16(a[mf][0], b0[nf][0], acc[4 + mf][nf], 0, 0, 0);
        acc[4 + mf][nf] = __builtin_amdgcn_mfma_f32_16x16x32_bf16(a[mf][1], b0[nf][1], acc[4 + mf][nf], 0, 0, 0);
      }
    __builtin_amdgcn_s_setprio(0);
    BAR();
  };

#pragma unroll 1
  for (int tt = 0; tt < TTN; tt += 2) {
    body(tt);                              // NT>=32 even: boundary only odd
    body(tt + 1);
    if (((tt + 1) % NT) == NT - 1)
      epilogue((tt + 1) / NT);             // per-panel store + acc reset
  }

  WAITVM(0);                   // trailing clamped DMAs must not outlive LDS
}

// ---------------------------------------------------------------------------
extern "C" void kernel_launch(void* const* d_in, const int* in_sizes, int n_in,
                              void* d_out, int out_size, void* d_ws, size_t ws_size,
                              hipStream_t stream) {
  const float* hs = (const float*)d_in[0];   // (8192, 2048)
  const float* w1 = (const float*)d_in[1];   // (8, 2048, 8192)
  const float* w2 = (const float*)d_in[2];   // (8, 4096, 2048)
  float* out = (float*)d_out;                // (8192, 2048) fp32
  char* ws = (char*)d_ws;

  const long HB_B  = (long)T_ * H_ * 2;      // 32 MiB hidden bf16
  const long ACT_B = (long)T_ * I_ * 2;      // 64 MiB acted bf16
  if (ws_size < (size_t)(HB_B + ACT_B)) return;

  unsigned short* hiddenB = (unsigned short*)(ws);
  unsigned short* acted   = (unsigned short*)(ws + HB_B);

  hipLaunchKernelGGL(convert_bf16, dim3(2048), dim3(256), 0, stream,
                     hs, hiddenB, (long)T_ * H_);

  // gemm1+SiLU: 1 round — grid 256 = 4 mb x 8 nbg x 8 e, 4 nb panels/block
  hipLaunchKernelGGL((gemm_fused<H_, 4, 32, 2 * I_, true>),
                     dim3(256), dim3(512), 131072, stream,
                     hiddenB, w1, acted,
                     (long)TPE * H_, (long)H_ * 2 * I_, (long)TPE * I_);

  // gemm2: unchanged single-pass (NBL=1), grid 256
  hipLaunchKernelGGL((gemm_fused<I_, 1, 8, H_, false>),
                     dim3(256), dim3(512), 131072, stream,
                     acted, w2, out,
                     (long)TPE * I_, (long)I_ * H_, (long)TPE * H_);
}

// Round 13
// 580.510 us; speedup vs baseline: 1.3657x; 1.3657x over previous
//
#include <hip/hip_runtime.h>

// ---------------------------------------------------------------------------
// Llama4TextExperts: per-expert  out = (up * silu(gate)) @ W2
// E=8, T=8192 (1024/expert), H=2048, I=4096, fp32 in/out, bf16 MFMA compute.
// R13: R5 (best verified: 525us) with a surgical schedule fix — ALL staging
//      issued at P3 (A q0+q1 DMA, B f4 x8), single vmcnt(0) at P2 (items are
//      >=2 phases old -> no stall), WRITEB at P2. Removes R5's P2 wait
//      sandwich AND its latent A(t+2)/P2-read race. Everything else
//      (B ownership, slot maps, epilogues, grids) identical to R5/R11.
// ---------------------------------------------------------------------------

#define E_   8
#define H_   2048
#define I_   4096
#define T_   8192
#define TPE  1024

typedef __bf16 bf16x8 __attribute__((ext_vector_type(8)));
typedef float  f32x4  __attribute__((ext_vector_type(4)));

__device__ __forceinline__ unsigned short f2bf(float f) {
  union { float f; unsigned int u; } v; v.f = f;
  unsigned int u = v.u;
  u += 0x7FFFu + ((u >> 16) & 1u);   // RNE
  return (unsigned short)(u >> 16);
}

__device__ __forceinline__ void async16(const void* g, void* l) {
  __builtin_amdgcn_global_load_lds(
      (__attribute__((address_space(1))) void*)(g),
      (__attribute__((address_space(3))) void*)(l), 16, 0, 0);
}

#define SB0()      __builtin_amdgcn_sched_barrier(0)
#define BAR()      __builtin_amdgcn_s_barrier()
#define WAITLGKM() asm volatile("s_waitcnt lgkmcnt(0)" ::: "memory")
#define WAITVM(n)  asm volatile("s_waitcnt vmcnt(" #n ")" ::: "memory")

// ---------------------------------------------------------------------------
__global__ void convert_bf16(const float* __restrict__ src,
                             unsigned short* __restrict__ dst, long n) {
  long i = ((long)blockIdx.x * blockDim.x + threadIdx.x) * 4;
  const long stride = (long)gridDim.x * blockDim.x * 4;
  for (; i < n; i += stride) {
    const float4 v = *(const float4*)&src[i];
    ushort4 o;
    o.x = f2bf(v.x); o.y = f2bf(v.y); o.z = f2bf(v.z); o.w = f2bf(v.w);
    *(ushort4*)&dst[i] = o;
  }
}

// ---------------------------------------------------------------------------
// 256x256x64 4-phase GEMM (R5 structure, P3-consolidated staging).
// A: bf16 (M,K) via global_load_lds (linear dest, pre-swizzled source,
// row-XOR &7). B: fp32 (K,N), per-thread float4 along N (lane owns 4
// contiguous cols = storage rows 4*lane..+3; wave = k-octet), reg transpose
// -> bf16x8 -> ds_write_b128 at slot = wave^(lane&7); frag reads quad-XOR.
// Schedule per tile t:
//   P0: read a(q0)+b0            | BAR lgkm MFMA BAR
//   P1: read b1                  | BAR lgkm MFMA BAR
//   P2: vmcnt(0) -> WRITEB B(t+1); read a(q1) | BAR lgkm MFMA BAR
//   P3: stage A(t+2) q0+q1 (DMA), LOADB B(t+2) | BAR MFMA(regs) BAR
// Ledger: only P3(t-1)'s 12 issues are in flight at P2(t) (>=2 phases old)
// -> vmcnt(0) proves B regs + A(t+1) landed pre-barrier. A(t+2) DMA targets
// buf[t&1] AFTER all tile-t reads of it (P3 > P2) -> WAR-clean.
// LDS 128KB: A[2][256][64] bf16 + B[2][256][64] bf16.
// ---------------------------------------------------------------------------
template <int K, int NBN, int LDB, bool SILU>
__global__ __launch_bounds__(512, 2)
void gemm_fused(const unsigned short* __restrict__ Aall,
                const float* __restrict__ Ball,
                void* __restrict__ Cout,
                long sA, long sB, long sC) {
  extern __shared__ char smem[];
  constexpr int NT = K / 64;

  const int tid  = threadIdx.x;
  const int wave = tid >> 6;
  const int lane = tid & 63;
  const int lr   = lane & 15;
  const int lq   = lane >> 4;
  const int wid_m = wave >> 2;     // 0..1
  const int wid_n = wave & 3;      // 0..3

  // T1: bijective XCD swizzle (gridDim.x % 8 == 0), mb innermost.
  const int nwg = gridDim.x;
  const int bid = blockIdx.x;
  const int wg  = (bid & 7) * (nwg >> 3) + (bid >> 3);
  const int mb  = wg & 3;
  const int tmp = wg >> 2;
  const int nb  = tmp % NBN;
  const int e   = tmp / NBN;

  const unsigned short* A = Aall + (long)e * sA + (long)(mb * 256) * K;
  const float*          B = Ball + (long)e * sB;

  // ---- A staging (global_load_lds, pre-swizzled source) ------------------
  const int stl  = tid >> 3;                      // 0..63
  const int scol = ((tid & 7) ^ (stl & 7)) * 8;   // swizzled src elem col

  auto stageA = [&](int bi, int q, int kt) {
    const long col = (long)kt * 64 + scol;
    char* l0 = smem + bi * 32768 + q * 16384 + wave * 1024;
    async16(A + (long)(q * 64 + stl) * K + col,        l0);
    async16(A + (long)(128 + q * 64 + stl) * K + col,  l0 + 8192);
  };

  // ---- B: lane owns storage rows 4*lane..4*lane+3 (contiguous global cols),
  //         wave owns k-octet. 8 float4 loads per tile.
  int colq;   // global col of storage row st = 4*lane (quad is contiguous)
  {
    const int st = 4 * lane;
    const int b  = st >> 7;
    const int r  = st & 127;
    const int w  = r >> 5;
    const int nf = (r >> 4) & 1;
    const int l4 = st & 15;
    if (SILU) colq = nb * 128 + (w * 32 + b * 16 + l4) + (nf ? I_ : 0);
    else      colq = nb * 256 + w * 64 + (b * 2 + nf) * 16 + l4;
  }
  const float* Bq = B + colq;

  f32x4 bv[8];
  auto LOADB = [&](int kt) {
    const long kbase = (long)kt * 64 + wave * 8;
#pragma unroll
    for (int i = 0; i < 8; ++i)
      bv[i] = *(const f32x4*)&Bq[(kbase + i) * (long)LDB];
  };
  auto WRITEB = [&](int bo) {
    char* LBw = smem + 65536 + bo * 32768;
    const int slot = wave ^ (lane & 7);           // (st>>2)&7 == lane&7
#pragma unroll
    for (int j = 0; j < 4; ++j) {
      bf16x8 pk;
#pragma unroll
      for (int i = 0; i < 8; ++i) pk[i] = (__bf16)bv[i][j];
      const int st = 4 * lane + j;
      *(bf16x8*)(LBw + st * 128 + slot * 16) = pk;
    }
  };

  // fragment-read swizzled slot offsets
  const int axA0 = ((0 + lq) ^ (lr & 7)) * 16;    // A: k 0..31
  const int axA1 = ((4 + lq) ^ (lr & 7)) * 16;    // A: k 32..63
  const int bxn[2] = { (lr >> 2), 4 + (lr >> 2) };  // B row-quad XOR per nf

  f32x4 acc[8][4];
#pragma unroll
  for (int m = 0; m < 8; ++m)
#pragma unroll
    for (int n = 0; n < 4; ++n) acc[m][n] = (f32x4)0.0f;

  // ---------------- prologue --------------------------------------------
  const int t1p = (NT > 1) ? 1 : 0;
  stageA(0, 0, 0);             // 2 a16  A(0)
  stageA(0, 1, 0);             // 2 a16
  LOADB(0);                    // 8 f4   B(0) -> bv
  SB0();
  WAITVM(0); SB0();            // A(0) landed, bv = B(0)
  WRITEB(0);                   // B(0) -> buf0
  WAITLGKM(); SB0();           // publish B(0); bv free
  stageA(1, 0, t1p);           // 2  A(1)q0 -> buf1 (not read until t=1)
  stageA(1, 1, t1p);           // 2  A(1)q1
  LOADB(t1p);                  // 8  B(1) -> bv
  SB0();
  BAR();                       // steady carry-in: [A(1)x4, B(1)x8] in flight

#pragma unroll 1
  for (int t = 0; t < NT; ++t) {
    const int cur = t & 1;
    const int bo  = cur ^ 1;
    const char* LA = smem + cur * 32768;
    const char* LB = smem + 65536 + cur * 32768;
    const int t2v = (t + 2 < NT) ? t + 2 : NT - 1;

    bf16x8 a[4][2], b0[2][2], b1[2][2];

    // ---- P0: read a(q0)+b0; no VMEM ------------------------------------
#pragma unroll
    for (int mf = 0; mf < 4; ++mf) {
      const int st = wid_m * 64 + mf * 16 + lr;
      a[mf][0] = *(const bf16x8*)(LA + st * 128 + axA0);
      a[mf][1] = *(const bf16x8*)(LA + st * 128 + axA1);
    }
#pragma unroll
    for (int nf = 0; nf < 2; ++nf) {
      const int st = wid_n * 32 + nf * 16 + lr;
      b0[nf][0] = *(const bf16x8*)(LB + st * 128 + ((0 + lq) ^ bxn[nf]) * 16);
      b0[nf][1] = *(const bf16x8*)(LB + st * 128 + ((4 + lq) ^ bxn[nf]) * 16);
    }
    SB0();
    BAR();
    WAITLGKM(); SB0();
    __builtin_amdgcn_s_setprio(1);
#pragma unroll
    for (int mf = 0; mf < 4; ++mf)
#pragma unroll
      for (int nf = 0; nf < 2; ++nf) {
        acc[mf][nf] = __builtin_amdgcn_mfma_f32_16x16x32_bf16(a[mf][0], b0[nf][0], acc[mf][nf], 0, 0, 0);
        acc[mf][nf] = __builtin_amdgcn_mfma_f32_16x16x32_bf16(a[mf][1], b0[nf][1], acc[mf][nf], 0, 0, 0);
      }
    __builtin_amdgcn_s_setprio(0);
    BAR();

    // ---- P1: read b1; no VMEM ------------------------------------------
#pragma unroll
    for (int nf = 0; nf < 2; ++nf) {
      const int st = 128 + wid_n * 32 + nf * 16 + lr;
      b1[nf][0] = *(const bf16x8*)(LB + st * 128 + ((0 + lq) ^ bxn[nf]) * 16);
      b1[nf][1] = *(const bf16x8*)(LB + st * 128 + ((4 + lq) ^ bxn[nf]) * 16);
    }
    SB0();
    BAR();
    WAITLGKM(); SB0();
    __builtin_amdgcn_s_setprio(1);
#pragma unroll
    for (int mf = 0; mf < 4; ++mf)
#pragma unroll
      for (int nf = 0; nf < 2; ++nf) {
        acc[mf][2 + nf] = __builtin_amdgcn_mfma_f32_16x16x32_bf16(a[mf][0], b1[nf][0], acc[mf][2 + nf], 0, 0, 0);
        acc[mf][2 + nf] = __builtin_amdgcn_mfma_f32_16x16x32_bf16(a[mf][1], b1[nf][1], acc[mf][2 + nf], 0, 0, 0);
      }
    __builtin_amdgcn_s_setprio(0);
    BAR();

    // ---- P2: vmcnt(0) -> WRITEB B(t+1); read a(q1) ---------------------
    WAITVM(0); SB0();          // all P3(t-1) issues landed (>=2 phases old):
                               // bv = B(t+1) ready, A(t+1) proven in LDS
    WRITEB(bo);
#pragma unroll
    for (int mf = 0; mf < 4; ++mf) {
      const int st = 128 + wid_m * 64 + mf * 16 + lr;
      a[mf][0] = *(const bf16x8*)(LA + st * 128 + axA0);
      a[mf][1] = *(const bf16x8*)(LA + st * 128 + axA1);
    }
    SB0();
    BAR();
    WAITLGKM(); SB0();         // a(q1) reads + B writes drained; bv free
    __builtin_amdgcn_s_setprio(1);
#pragma unroll
    for (int mf = 0; mf < 4; ++mf)
#pragma unroll
      for (int nf = 0; nf < 2; ++nf) {
        acc[4 + mf][2 + nf] = __builtin_amdgcn_mfma_f32_16x16x32_bf16(a[mf][0], b1[nf][0], acc[4 + mf][2 + nf], 0, 0, 0);
        acc[4 + mf][2 + nf] = __builtin_amdgcn_mfma_f32_16x16x32_bf16(a[mf][1], b1[nf][1], acc[4 + mf][2 + nf], 0, 0, 0);
      }
    __builtin_amdgcn_s_setprio(0);
    BAR();

    // ---- P3: issue ALL staging for t+2; MFMA on regs -------------------
    stageA(cur, 0, t2v);       // 2  A(t+2)q0 -> buf cur (tile-t reads done)
    stageA(cur, 1, t2v);       // 2  A(t+2)q1
    LOADB(t2v);                // 8  B(t+2) -> bv (WAR ok: lgkm drained @P2)
    SB0();
    BAR();
    __builtin_amdgcn_s_setprio(1);
#pragma unroll
    for (int mf = 0; mf < 4; ++mf)
#pragma unroll
      for (int nf = 0; nf < 2; ++nf) {
        acc[4 + mf][nf] = __builtin_amdgcn_mfma_f32_16x16x32_bf16(a[mf][0], b0[nf][0], acc[4 + mf][nf], 0, 0, 0);
        acc[4 + mf][nf] = __builtin_amdgcn_mfma_f32_16x16x32_bf16(a[mf][1], b0[nf][1], acc[4 + mf][nf], 0, 0, 0);
      }
    __builtin_amdgcn_s_setprio(0);
    BAR();
  }

  WAITVM(0);                   // trailing clamped loads must not outlive LDS

  // ---------------- epilogue (C/D: col=lane&15, row=(lane>>4)*4+r) -------
  if (SILU) {
    unsigned short* Cc = (unsigned short*)Cout + (long)e * sC;
#pragma unroll
    for (int mf = 0; mf < 8; ++mf)
#pragma unroll
      for (int p = 0; p < 2; ++p)
#pragma unroll
        for (int rr = 0; rr < 4; ++rr) {
          const int row = mb * 256 + wid_m * 128 + mf * 16 + lq * 4 + rr;
          const int col = nb * 128 + wid_n * 32 + p * 16 + lr;
          const float g = acc[mf][p * 2][rr];
          const float u = acc[mf][p * 2 + 1][rr];
          Cc[(long)row * I_ + col] = f2bf(u * (g / (1.0f + __expf(-g))));
        }
  } else {
    float* Cc = (float*)Cout + (long)e * sC;
#pragma unroll
    for (int mf = 0; mf < 8; ++mf)
#pragma unroll
      for (int q = 0; q < 4; ++q)
#pragma unroll
        for (int rr = 0; rr < 4; ++rr) {
          const int row = mb * 256 + wid_m * 128 + mf * 16 + lq * 4 + rr;
          const int col = nb * 256 + wid_n * 64 + q * 16 + lr;
          Cc[(long)row * H_ + col] = acc[mf][q][rr];
        }
  }
}

// ---------------------------------------------------------------------------
extern "C" void kernel_launch(void* const* d_in, const int* in_sizes, int n_in,
                              void* d_out, int out_size, void* d_ws, size_t ws_size,
                              hipStream_t stream) {
  const float* hs = (const float*)d_in[0];   // (8192, 2048)
  const float* w1 = (const float*)d_in[1];   // (8, 2048, 8192)
  const float* w2 = (const float*)d_in[2];   // (8, 4096, 2048)
  float* out = (float*)d_out;                // (8192, 2048) fp32
  char* ws = (char*)d_ws;

  const long HB_B  = (long)T_ * H_ * 2;      // 32 MiB hidden bf16
  const long ACT_B = (long)T_ * I_ * 2;      // 64 MiB acted bf16
  if (ws_size < (size_t)(HB_B + ACT_B)) return;

  unsigned short* hiddenB = (unsigned short*)(ws);
  unsigned short* acted   = (unsigned short*)(ws + HB_B);

  hipLaunchKernelGGL(convert_bf16, dim3(2048), dim3(256), 0, stream,
                     hs, hiddenB, (long)T_ * H_);

  // gemm1+SiLU: A=hiddenB (TPE,H), B=W1 (H,2I) fp32 direct -> acted bf16
  hipLaunchKernelGGL((gemm_fused<H_, 32, 2 * I_, true>),
                     dim3(1024), dim3(512), 131072, stream,
                     hiddenB, w1, acted,
                     (long)TPE * H_, (long)H_ * 2 * I_, (long)TPE * I_);

  // gemm2: A=acted (TPE,I), B=W2 (I,H) fp32 direct -> out fp32
  hipLaunchKernelGGL((gemm_fused<I_, 8, H_, false>),
                     dim3(256), dim3(512), 131072, stream,
                     acted, w2, out,
                     (long)TPE * I_, (long)I_ * H_, (long)TPE * H_);
}